// Round 5
// baseline (323.726 us; speedup 1.0000x reference)
//
#include <hip/hip_runtime.h>
#include <hip/hip_bf16.h>

#define TT 2048

typedef __attribute__((ext_vector_type(8))) short bf16x8;
typedef __attribute__((ext_vector_type(4))) float f32x4;
typedef __attribute__((ext_vector_type(8))) unsigned short us8;
typedef __attribute__((ext_vector_type(4))) unsigned short us4;

typedef __attribute__((address_space(1))) void gvoid;
typedef __attribute__((address_space(3))) void svoid;

__device__ __forceinline__ void gll16(const void* g, void* l) {
    __builtin_amdgcn_global_load_lds((gvoid*)g, (svoid*)l, 16, 0, 0);
}

__device__ __forceinline__ unsigned short f2bf(float f) {
    union { float f; unsigned u; } v; v.f = f;
    unsigned r = v.u + 0x7fffu + ((v.u >> 16) & 1u);
    return (unsigned short)(r >> 16);
}
__device__ __forceinline__ float bf2f(unsigned short u) {
    union { unsigned u; float f; } v; v.u = ((unsigned)u) << 16;
    return v.f;
}

#define MFMA16(a, b, c) __builtin_amdgcn_mfma_f32_16x16x32_bf16((a), (b), (c), 0, 0, 0)

// ---------------------------------------------------------------------------
// x fp32 -> hi/lo bf16 (row-major). 4096*1024 elements, 8/thread.
__global__ __launch_bounds__(256) void convert_x(const float* __restrict__ x,
                                                 unsigned short* __restrict__ xh,
                                                 unsigned short* __restrict__ xl) {
    const int i = blockIdx.x * 256 + threadIdx.x;
    const float4 a = ((const float4*)x)[2 * i];
    const float4 b = ((const float4*)x)[2 * i + 1];
    const float v[8] = {a.x, a.y, a.z, a.w, b.x, b.y, b.z, b.w};
    us8 H, L;
    #pragma unroll
    for (int j = 0; j < 8; ++j) {
        const unsigned short h = f2bf(v[j]);
        H[j] = h;
        L[j] = f2bf(v[j] - bf2f(h));
    }
    ((us8*)xh)[i] = H;
    ((us8*)xl)[i] = L;
}

// ---------------------------------------------------------------------------
// One weight [1024][1024] fp32 -> hi/lo bf16 [n][k] (transposed).
__global__ __launch_bounds__(256) void convert_w(const float* __restrict__ W,
                                                 unsigned short* __restrict__ Wh,
                                                 unsigned short* __restrict__ Wl) {
    __shared__ float tile[32 * 33];
    const int t = threadIdx.x;
    const int k0 = blockIdx.x * 32, n0 = blockIdx.y * 32;

    const int kl_ = t >> 3, nc = (t & 7) * 4;
    const float4 v = *(const float4*)&W[(size_t)(k0 + kl_) * 1024 + n0 + nc];
    tile[(nc + 0) * 33 + kl_] = v.x;
    tile[(nc + 1) * 33 + kl_] = v.y;
    tile[(nc + 2) * 33 + kl_] = v.z;
    tile[(nc + 3) * 33 + kl_] = v.w;
    __syncthreads();
    const int nl = t >> 3, kc = (t & 7) * 4;
    us4 H, L;
    #pragma unroll
    for (int j = 0; j < 4; ++j) {
        const float f = tile[nl * 33 + kc + j];
        const unsigned short h = f2bf(f);
        H[j] = h;
        L[j] = f2bf(f - bf2f(h));
    }
    *(us4*)&Wh[(size_t)(n0 + nl) * 1024 + k0 + kc] = H;
    *(us4*)&Wl[(size_t)(n0 + nl) * 1024 + k0 + kc] = L;
}

// ---------------------------------------------------------------------------
// Split-bf16 GEMM v2: O = A @ Bt^T + bias. BK=32, block tile BM x 128,
// 4 waves (2x2), wave tile (BM/2) x 64: 16 ds_read per 48 MFMA (1:3 ratio).
// Staging swizzle: 8-elem col-block of row r stored at slot (blk ^ ((r>>1)&3)).
// OUTMODE 0: hi/lo bf16 out, stride 2048 (fused QK; bias0=cols<1024, bias1=rest)
// OUTMODE 2: fp32 out, stride 1024
// OUTMODE 3: bf16 hi out TRANSPOSED as V[b][n][d][t] (stride 2048 in t)
template <int BM, int OUTMODE>
__global__ __launch_bounds__(256, 2)
void proj2(const unsigned short* __restrict__ Ah, const unsigned short* __restrict__ Al,
           const unsigned short* __restrict__ Bh, const unsigned short* __restrict__ Bl,
           const float* __restrict__ bias0, const float* __restrict__ bias1,
           unsigned short* __restrict__ Oh, unsigned short* __restrict__ Ol,
           float* __restrict__ Of) {
    constexpr int MT = BM / 32;          // m-frags per wave (4 or 2)
    constexpr int RW = BM / 2;           // rows per wave
    constexpr int CA = BM / 64;          // A chunks per wave per buffer
    __shared__ __align__(16) unsigned short sm[BM * 64 + 8192];
    unsigned short* sAh = sm;                    // [BM][32]
    unsigned short* sAl = sm + BM * 32;
    unsigned short* sBh = sm + BM * 64;          // [128][32]
    unsigned short* sBl = sm + BM * 64 + 4096;

    const int t = threadIdx.x;
    const int lane = t & 63, w = t >> 6;
    const int wr = w >> 1, wc = w & 1;
    const int l15 = lane & 15, lq = lane >> 4;

    // XCD-aware bijective swizzle (nwg % 8 == 0 for all our grids)
    const int nwg = gridDim.x * gridDim.y;
    const int bid = blockIdx.y * gridDim.x + blockIdx.x;
    const int swz = (bid & 7) * (nwg >> 3) + (bid >> 3);
    const int bx = swz % gridDim.x, by = swz / gridDim.x;
    const int row0 = bx * BM;
    const int col0 = by * 128;

    f32x4 acc[MT][4] = {};

    for (int k0 = 0; k0 < 1024; k0 += 32) {
        __syncthreads();
        #pragma unroll
        for (int cc = 0; cc < CA; ++cc) {        // A tile: hi + lo
            const int c = w * CA + cc;
            const int r = c * 16 + (lane >> 2);
            const int src = (row0 + r) * 1024 + k0 + 8 * ((lane & 3) ^ ((r >> 1) & 3));
            gll16(&Ah[src], &sAh[c * 512]);
            gll16(&Al[src], &sAl[c * 512]);
        }
        #pragma unroll
        for (int cc = 0; cc < 2; ++cc) {         // B tile (128 rows)
            const int c = w * 2 + cc;
            const int r = c * 16 + (lane >> 2);
            const int src = (col0 + r) * 1024 + k0 + 8 * ((lane & 3) ^ ((r >> 1) & 3));
            gll16(&Bh[src], &sBh[c * 512]);
            gll16(&Bl[src], &sBl[c * 512]);
        }
        __syncthreads();

        bf16x8 aH[MT], aL[MT], bH[4], bL[4];
        #pragma unroll
        for (int nt = 0; nt < 4; ++nt) {
            const int rn = 64 * wc + 16 * nt + l15;
            const int off = rn * 32 + 8 * (lq ^ ((rn >> 1) & 3));
            bH[nt] = *(const bf16x8*)&sBh[off];
            bL[nt] = *(const bf16x8*)&sBl[off];
        }
        #pragma unroll
        for (int mt = 0; mt < MT; ++mt) {
            const int rm = RW * wr + 16 * mt + l15;
            const int off = rm * 32 + 8 * (lq ^ ((rm >> 1) & 3));
            aH[mt] = *(const bf16x8*)&sAh[off];
            aL[mt] = *(const bf16x8*)&sAl[off];
        }
        #pragma unroll
        for (int mt = 0; mt < MT; ++mt)
            #pragma unroll
            for (int nt = 0; nt < 4; ++nt) {
                acc[mt][nt] = MFMA16(aH[mt], bH[nt], acc[mt][nt]);
                acc[mt][nt] = MFMA16(aH[mt], bL[nt], acc[mt][nt]);
                acc[mt][nt] = MFMA16(aL[mt], bH[nt], acc[mt][nt]);
            }
    }

    if (OUTMODE == 3) {
        // direct transposed store: V[((b*16 + c>>6)*64 + c&63)][t], us4 along t
        #pragma unroll
        for (int mt = 0; mt < MT; ++mt)
            #pragma unroll
            for (int nt = 0; nt < 4; ++nt) {
                const int c = col0 + 64 * wc + 16 * nt + l15;
                const float bb = bias0[c];
                const int gr0 = row0 + RW * wr + 16 * mt + 4 * lq;
                const int b = gr0 >> 11, t0 = gr0 & 2047;
                us4 o4;
                #pragma unroll
                for (int r = 0; r < 4; ++r) o4[r] = f2bf(acc[mt][nt][r] + bb);
                *(us4*)&Oh[((size_t)((b * 16 + (c >> 6)) * 64 + (c & 63))) * 2048 + t0] = o4;
            }
        return;
    }

    // LDS-bounce epilogue, two 32-col passes (fits LDS exactly for BM=128)
    __syncthreads();   // all waves done reading sA/sB
    float* sc = (float*)sm + w * (RW * 32);
    #pragma unroll
    for (int h = 0; h < 2; ++h) {
        #pragma unroll
        for (int mt = 0; mt < MT; ++mt)
            #pragma unroll
            for (int nt2 = 0; nt2 < 2; ++nt2) {
                const int nt = 2 * h + nt2;
                const int colg = col0 + 64 * wc + 16 * nt + l15;
                float bb;
                if (OUTMODE == 0) bb = (col0 < 1024) ? bias0[colg] : bias1[colg - 1024];
                else bb = bias0[colg];
                const int cl = 16 * nt2 + l15;
                #pragma unroll
                for (int r = 0; r < 4; ++r) {
                    const int row = 16 * mt + 4 * lq + r;
                    sc[row * 32 + 4 * ((cl >> 2) ^ (row & 7)) + (cl & 3)] = acc[mt][nt][r] + bb;
                }
            }
        asm volatile("" ::: "memory");
        #pragma unroll
        for (int it = 0; it < RW / 16; ++it) {
            const int rl = it * 16 + (lane >> 2);
            const int c8 = (lane & 3) * 8;
            const float4 f0 = *(const float4*)&sc[rl * 32 + 4 * ((c8 >> 2) ^ (rl & 7))];
            const float4 f1 = *(const float4*)&sc[rl * 32 + 4 * (((c8 >> 2) + 1) ^ (rl & 7))];
            const int gr = row0 + RW * wr + rl;
            const int gc = col0 + 64 * wc + 32 * h + c8;
            if (OUTMODE == 2) {
                *(float4*)&Of[(size_t)gr * 1024 + gc] = f0;
                *(float4*)&Of[(size_t)gr * 1024 + gc + 4] = f1;
            } else {
                const float v[8] = {f0.x, f0.y, f0.z, f0.w, f1.x, f1.y, f1.z, f1.w};
                us8 H, L;
                #pragma unroll
                for (int j = 0; j < 8; ++j) {
                    const unsigned short hh = f2bf(v[j]);
                    H[j] = hh;
                    L[j] = f2bf(v[j] - bf2f(hh));
                }
                *(us8*)&Oh[(size_t)gr * 2048 + gc] = H;
                *(us8*)&Ol[(size_t)gr * 2048 + gc] = L;
            }
        }
        asm volatile("" ::: "memory");
    }
}

// ---------------------------------------------------------------------------
// Flash attention v2 (swapped roles). QK buffer [4096][2048]: cols 0-1023 =
// q-proj (column side), 1024-2047 = k-proj (row side). V pre-transposed
// [b][n][64 d][2048 t]. Q frags hoisted; sP aliases dead sQ (40 KB LDS);
// defer-max; setprio around MFMA clusters.
__global__ __launch_bounds__(256, 4)
void attn2(const unsigned short* __restrict__ QKh, const unsigned short* __restrict__ QKl,
           const unsigned short* __restrict__ Vt,
           unsigned short* __restrict__ Oh, unsigned short* __restrict__ Ol) {
    __shared__ __align__(16) unsigned short sm[20480];   // 40 KB
    unsigned short* sQh = sm;            // [64][64] (dead after hoist; sP aliases)
    unsigned short* sQl = sm + 4096;
    unsigned short* sKh = sm + 8192;
    unsigned short* sKl = sm + 12288;
    unsigned short* sVt = sm + 16384;    // [64 d][64 t]
    unsigned short* sP  = sm;            // 4 waves x [16][64]

    const int t = threadIdx.x;
    const int lane = t & 63, w = t >> 6;
    const int l15 = lane & 15, lq = lane >> 4;
    const int bn = blockIdx.x;
    const int b = bn >> 4, n = bn & 15;
    const int qt = (gridDim.y - 1) - blockIdx.y;         // heavy tiles first
    const int rowQ0 = b * TT + qt * 64;
    const int colQ = 1024 + n * 64;                      // row side = k-proj
    const int colK = n * 64;                             // col side = q-proj

    // stage Q tile (row side), hi+lo
    #pragma unroll
    for (int cc = 0; cc < 2; ++cc) {
        const int c = w * 2 + cc;
        const int r = 8 * c + (lane >> 3);
        const int src = (rowQ0 + r) * 2048 + colQ + 8 * ((lane & 7) ^ (r & 7));
        gll16(&QKh[src], &sQh[c * 512]);
        gll16(&QKl[src], &sQl[c * 512]);
    }
    __syncthreads();
    // hoist Q fragments (loop-invariant)
    bf16x8 qH[2], qL[2];
    #pragma unroll
    for (int kh = 0; kh < 2; ++kh) {
        const int rq = 16 * w + l15;
        const int off = rq * 64 + 8 * ((lq + 4 * kh) ^ (rq & 7));
        qH[kh] = *(const bf16x8*)&sQh[off];
        qL[kh] = *(const bf16x8*)&sQl[off];
    }

    float m_[4], l_[4];
    f32x4 o[4] = {};
    #pragma unroll
    for (int r = 0; r < 4; ++r) { m_[r] = -1e30f; l_[r] = 0.f; }

    for (int kt = 0; kt <= qt; ++kt) {
        const int rowK0 = b * TT + kt * 64;
        __syncthreads();                                  // prev iter done with LDS
        #pragma unroll
        for (int cc = 0; cc < 2; ++cc) {                  // K hi/lo (col side)
            const int c = w * 2 + cc;
            const int r = 8 * c + (lane >> 3);
            const int src = (rowK0 + r) * 2048 + colK + 8 * ((lane & 7) ^ (r & 7));
            gll16(&QKh[src], &sKh[c * 512]);
            gll16(&QKl[src], &sKl[c * 512]);
        }
        #pragma unroll
        for (int cc = 0; cc < 2; ++cc) {                  // V (pre-transposed rows d)
            const int c = w * 2 + cc;
            const int r = 8 * c + (lane >> 3);
            const int src = (bn * 64 + r) * 2048 + kt * 64 + 8 * ((lane & 7) ^ (r & 7));
            gll16(&Vt[src], &sVt[c * 512]);
        }
        __syncthreads();

        // ---- QK^T (split: 3 MFMA per 16x16x32)
        f32x4 s[4] = {};
        const int njt = (kt == qt) ? (w + 1) : 4;         // skip fully-masked tiles
        __builtin_amdgcn_s_setprio(1);
        #pragma unroll
        for (int kh = 0; kh < 2; ++kh) {
            #pragma unroll
            for (int jt = 0; jt < 4; ++jt) {
                if (jt >= njt) continue;                  // wave-uniform
                const int rk = 16 * jt + l15;
                const int offk = rk * 64 + 8 * ((lq + 4 * kh) ^ (rk & 7));
                const bf16x8 kH = *(const bf16x8*)&sKh[offk];
                const bf16x8 kL = *(const bf16x8*)&sKl[offk];
                s[jt] = MFMA16(qH[kh], kH, s[jt]);
                s[jt] = MFMA16(qH[kh], kL, s[jt]);
                s[jt] = MFMA16(qL[kh], kH, s[jt]);
            }
        }
        __builtin_amdgcn_s_setprio(0);
        if (kt == qt) {                                    // causal mask on diagonal
            #pragma unroll
            for (int jt = 0; jt < 4; ++jt)
                #pragma unroll
                for (int r = 0; r < 4; ++r)
                    if (16 * jt + l15 > 16 * w + 4 * lq + r) s[jt][r] = -1e30f;
        }

        // ---- online softmax with defer-max (THR=16 raw logits -> exp arg <= 2)
        float mx[4];
        int need = 0;
        #pragma unroll
        for (int r = 0; r < 4; ++r) {
            float m0 = fmaxf(fmaxf(s[0][r], s[1][r]), fmaxf(s[2][r], s[3][r]));
            #pragma unroll
            for (int off = 8; off; off >>= 1) m0 = fmaxf(m0, __shfl_xor(m0, off, 16));
            mx[r] = m0;
            need |= (m0 > m_[r] + 16.f) ? 1 : 0;
        }
        float po[4][4];
        if (__any(need)) {
            #pragma unroll
            for (int r = 0; r < 4; ++r) {
                const float mnew = fmaxf(m_[r], mx[r]);
                const float alpha = __expf((m_[r] - mnew) * 0.125f);
                m_[r] = mnew;
                float ps = 0.f;
                #pragma unroll
                for (int jt = 0; jt < 4; ++jt) {
                    const float p = __expf((s[jt][r] - mnew) * 0.125f);
                    po[r][jt] = p;
                    ps += p;
                }
                #pragma unroll
                for (int off = 8; off; off >>= 1) ps += __shfl_xor(ps, off, 16);
                l_[r] = l_[r] * alpha + ps;
                #pragma unroll
                for (int dt = 0; dt < 4; ++dt) o[dt][r] *= alpha;
            }
        } else {
            #pragma unroll
            for (int r = 0; r < 4; ++r) {
                float ps = 0.f;
                #pragma unroll
                for (int jt = 0; jt < 4; ++jt) {
                    const float p = __expf((s[jt][r] - m_[r]) * 0.125f);
                    po[r][jt] = p;
                    ps += p;
                }
                #pragma unroll
                for (int off = 8; off; off >>= 1) ps += __shfl_xor(ps, off, 16);
                l_[r] += ps;
            }
        }
        // write P (bf16) to per-wave LDS region (aliases dead sQ)
        unsigned short* Pw = sP + w * 1024;
        #pragma unroll
        for (int r = 0; r < 4; ++r) {
            const int rl = 4 * lq + r;
            #pragma unroll
            for (int jt = 0; jt < 4; ++jt) {
                const int c = 16 * jt + l15;
                Pw[rl * 64 + 8 * ((c >> 3) ^ (rl & 7)) + (c & 7)] = f2bf(po[r][jt]);
            }
        }
        __syncthreads();

        // ---- PV (plain bf16; V already transposed in LDS)
        __builtin_amdgcn_s_setprio(1);
        #pragma unroll
        for (int kh = 0; kh < 2; ++kh) {
            const int offp = l15 * 64 + 8 * ((lq + 4 * kh) ^ (l15 & 7));
            const bf16x8 pa = *(const bf16x8*)&Pw[offp];
            #pragma unroll
            for (int dt = 0; dt < 4; ++dt) {
                const int rd = 16 * dt + l15;
                const int offv = rd * 64 + 8 * ((lq + 4 * kh) ^ (rd & 7));
                const bf16x8 vb = *(const bf16x8*)&sVt[offv];
                o[dt] = MFMA16(pa, vb, o[dt]);
            }
        }
        __builtin_amdgcn_s_setprio(0);
    }

    // ---- epilogue: normalize, bounce through LDS, store hi/lo bf16
    __syncthreads();   // sP aliases sc region across waves — drain loop reads
    float inv[4];
    #pragma unroll
    for (int r = 0; r < 4; ++r) inv[r] = 1.0f / l_[r];
    float* sc = (float*)sm + w * (16 * 68);
    #pragma unroll
    for (int dt = 0; dt < 4; ++dt)
        #pragma unroll
        for (int r = 0; r < 4; ++r)
            sc[(4 * lq + r) * 68 + 16 * dt + l15] = o[dt][r] * inv[r];
    asm volatile("" ::: "memory");
    #pragma unroll
    for (int it = 0; it < 2; ++it) {
        const int rl = 8 * it + (lane >> 3);
        const int c8 = (lane & 7) * 8;
        const float4 f0 = *(const float4*)&sc[rl * 68 + c8];
        const float4 f1 = *(const float4*)&sc[rl * 68 + c8 + 4];
        const float v[8] = {f0.x, f0.y, f0.z, f0.w, f1.x, f1.y, f1.z, f1.w};
        us8 H, L;
        #pragma unroll
        for (int j = 0; j < 8; ++j) {
            const unsigned short h = f2bf(v[j]);
            H[j] = h;
            L[j] = f2bf(v[j] - bf2f(h));
        }
        const int gt = rowQ0 + 16 * w + rl;
        *(us8*)&Oh[(size_t)gt * 1024 + (n * 64) + c8] = H;
        *(us8*)&Ol[(size_t)gt * 1024 + (n * 64) + c8] = L;
    }
}

// ---------------------------------------------------------------------------
extern "C" void kernel_launch(void* const* d_in, const int* in_sizes, int n_in,
                              void* d_out, int out_size, void* d_ws, size_t ws_size,
                              hipStream_t stream) {
    const float* x  = (const float*)d_in[0];
    const float* Wq = (const float*)d_in[1];
    const float* bq = (const float*)d_in[2];
    const float* Wk = (const float*)d_in[3];
    const float* bk = (const float*)d_in[4];
    const float* Wv = (const float*)d_in[5];
    const float* bv = (const float*)d_in[6];
    const float* Wp = (const float*)d_in[7];
    const float* bp = (const float*)d_in[8];
    float* out = (float*)d_out;

    char* p = (char*)d_ws;                                 // peak 64 MiB exactly
    const size_t MB = 1024 * 1024;
    unsigned short* xh  = (unsigned short*)(p);            //  8 MB
    unsigned short* xl  = (unsigned short*)(p +  8 * MB);  //  8 MB
    unsigned short* qkh = (unsigned short*)(p + 16 * MB);  // 16 MB [4096][2048]
    unsigned short* qkl = (unsigned short*)(p + 32 * MB);  // 16 MB
    unsigned short* vh  = (unsigned short*)(p + 48 * MB);  //  8 MB [32][64][2048]
    unsigned short* wbh = (unsigned short*)(p + 56 * MB);  //  4 MB (QK Bt hi)
    unsigned short* wbl = (unsigned short*)(p + 60 * MB);  //  4 MB (QK Bt lo)
    unsigned short* wsh = (unsigned short*)(p + 56 * MB);  //  2 MB (single-W hi)
    unsigned short* wsl = (unsigned short*)(p + 58 * MB);  //  2 MB (single-W lo)
    unsigned short* oh = xh;                               // x dead after projections
    unsigned short* ol = xl;

    const dim3 blk(256);
    const dim3 gw(32, 32);

    convert_x<<<2048, blk, 0, stream>>>(x, xh, xl);

    // fused q+k projection: Bt rows 0-1023 = Wq, 1024-2047 = Wk
    convert_w<<<gw, blk, 0, stream>>>(Wq, wbh, wbl);
    convert_w<<<gw, blk, 0, stream>>>(Wk, wbh + 1024 * 1024, wbl + 1024 * 1024);
    proj2<128, 0><<<dim3(32, 16), blk, 0, stream>>>(xh, xl, wbh, wbl, bq, bk,
                                                    qkh, qkl, nullptr);
    // v projection, output pre-transposed [b][n][d][t]
    convert_w<<<gw, blk, 0, stream>>>(Wv, wsh, wsl);
    proj2<64, 3><<<dim3(64, 8), blk, 0, stream>>>(xh, xl, wsh, wsl, bv, nullptr,
                                                  vh, nullptr, nullptr);

    attn2<<<dim3(32, 32), blk, 0, stream>>>(qkh, qkl, vh, oh, ol);

    // final projection -> fp32 out
    convert_w<<<gw, blk, 0, stream>>>(Wp, wsh, wsl);
    proj2<64, 2><<<dim3(64, 8), blk, 0, stream>>>(oh, ol, wsh, wsl, bp, nullptr,
                                                  nullptr, nullptr, out);
}

// Round 9
// 316.594 us; speedup vs baseline: 1.0225x; 1.0225x over previous
//
#include <hip/hip_runtime.h>
#include <hip/hip_bf16.h>

#define TT 2048

typedef __attribute__((ext_vector_type(8))) short bf16x8;
typedef __attribute__((ext_vector_type(4))) float f32x4;
typedef __attribute__((ext_vector_type(8))) unsigned short us8;
typedef __attribute__((ext_vector_type(4))) unsigned short us4;

typedef __attribute__((address_space(1))) void gvoid;
typedef __attribute__((address_space(3))) void svoid;

__device__ __forceinline__ void gll16(const void* g, void* l) {
    __builtin_amdgcn_global_load_lds((gvoid*)g, (svoid*)l, 16, 0, 0);
}

__device__ __forceinline__ unsigned short f2bf(float f) {
    union { float f; unsigned u; } v; v.f = f;
    unsigned r = v.u + 0x7fffu + ((v.u >> 16) & 1u);
    return (unsigned short)(r >> 16);
}
__device__ __forceinline__ float bf2f(unsigned short u) {
    union { unsigned u; float f; } v; v.u = ((unsigned)u) << 16;
    return v.f;
}

#define MFMA16(a, b, c) __builtin_amdgcn_mfma_f32_16x16x32_bf16((a), (b), (c), 0, 0, 0)

// ---------------------------------------------------------------------------
// x fp32 -> hi/lo bf16 (row-major). 4096*1024 elements, 8/thread.
__global__ __launch_bounds__(256) void convert_x(const float* __restrict__ x,
                                                 unsigned short* __restrict__ xh,
                                                 unsigned short* __restrict__ xl) {
    const int i = blockIdx.x * 256 + threadIdx.x;
    const float4 a = ((const float4*)x)[2 * i];
    const float4 b = ((const float4*)x)[2 * i + 1];
    const float v[8] = {a.x, a.y, a.z, a.w, b.x, b.y, b.z, b.w};
    us8 H, L;
    #pragma unroll
    for (int j = 0; j < 8; ++j) {
        const unsigned short h = f2bf(v[j]);
        H[j] = h;
        L[j] = f2bf(v[j] - bf2f(h));
    }
    ((us8*)xh)[i] = H;
    ((us8*)xl)[i] = L;
}

// ---------------------------------------------------------------------------
// One weight [1024][1024] fp32 -> hi/lo bf16 [n][k] (transposed).
__global__ __launch_bounds__(256) void convert_w(const float* __restrict__ W,
                                                 unsigned short* __restrict__ Wh,
                                                 unsigned short* __restrict__ Wl) {
    __shared__ float tile[32 * 33];
    const int t = threadIdx.x;
    const int k0 = blockIdx.x * 32, n0 = blockIdx.y * 32;

    const int kl_ = t >> 3, nc = (t & 7) * 4;
    const float4 v = *(const float4*)&W[(size_t)(k0 + kl_) * 1024 + n0 + nc];
    tile[(nc + 0) * 33 + kl_] = v.x;
    tile[(nc + 1) * 33 + kl_] = v.y;
    tile[(nc + 2) * 33 + kl_] = v.z;
    tile[(nc + 3) * 33 + kl_] = v.w;
    __syncthreads();
    const int nl = t >> 3, kc = (t & 7) * 4;
    us4 H, L;
    #pragma unroll
    for (int j = 0; j < 4; ++j) {
        const float f = tile[nl * 33 + kc + j];
        const unsigned short h = f2bf(f);
        H[j] = h;
        L[j] = f2bf(f - bf2f(h));
    }
    *(us4*)&Wh[(size_t)(n0 + nl) * 1024 + k0 + kc] = H;
    *(us4*)&Wl[(size_t)(n0 + nl) * 1024 + k0 + kc] = L;
}

// ---------------------------------------------------------------------------
// Split-bf16 GEMM v2: O = A @ Bt^T + bias. BK=32, block tile BM x 128,
// 4 waves (2x2), wave tile (BM/2) x 64: 16 ds_read per 48 MFMA (1:3 ratio).
// Staging swizzle: 8-elem col-block of row r stored at slot (blk ^ ((r>>1)&3)).
// OUTMODE 0: hi/lo bf16 out, stride 2048 (fused QK; bias0=cols<1024, bias1=rest)
// OUTMODE 2: fp32 out, stride 1024
// OUTMODE 3: bf16 hi out TRANSPOSED as V[b][n][d][t], coalesced via LDS bounce
template <int BM, int OUTMODE>
__global__ __launch_bounds__(256, 2)
void proj2(const unsigned short* __restrict__ Ah, const unsigned short* __restrict__ Al,
           const unsigned short* __restrict__ Bh, const unsigned short* __restrict__ Bl,
           const float* __restrict__ bias0, const float* __restrict__ bias1,
           unsigned short* __restrict__ Oh, unsigned short* __restrict__ Ol,
           float* __restrict__ Of) {
    constexpr int MT = BM / 32;          // m-frags per wave (4 or 2)
    constexpr int RW = BM / 2;           // rows per wave
    constexpr int CA = BM / 64;          // A chunks per wave per buffer
    __shared__ __align__(16) unsigned short sm[BM * 64 + 8192];
    unsigned short* sAh = sm;                    // [BM][32]
    unsigned short* sAl = sm + BM * 32;
    unsigned short* sBh = sm + BM * 64;          // [128][32]
    unsigned short* sBl = sm + BM * 64 + 4096;

    const int t = threadIdx.x;
    const int lane = t & 63, w = t >> 6;
    const int wr = w >> 1, wc = w & 1;
    const int l15 = lane & 15, lq = lane >> 4;

    // XCD-aware bijective swizzle (nwg % 8 == 0 for all our grids)
    const int nwg = gridDim.x * gridDim.y;
    const int bid = blockIdx.y * gridDim.x + blockIdx.x;
    const int swz = (bid & 7) * (nwg >> 3) + (bid >> 3);
    const int bx = swz % gridDim.x, by = swz / gridDim.x;
    const int row0 = bx * BM;
    const int col0 = by * 128;

    f32x4 acc[MT][4] = {};

    for (int k0 = 0; k0 < 1024; k0 += 32) {
        __syncthreads();
        #pragma unroll
        for (int cc = 0; cc < CA; ++cc) {        // A tile: hi + lo
            const int c = w * CA + cc;
            const int r = c * 16 + (lane >> 2);
            const int src = (row0 + r) * 1024 + k0 + 8 * ((lane & 3) ^ ((r >> 1) & 3));
            gll16(&Ah[src], &sAh[c * 512]);
            gll16(&Al[src], &sAl[c * 512]);
        }
        #pragma unroll
        for (int cc = 0; cc < 2; ++cc) {         // B tile (128 rows)
            const int c = w * 2 + cc;
            const int r = c * 16 + (lane >> 2);
            const int src = (col0 + r) * 1024 + k0 + 8 * ((lane & 3) ^ ((r >> 1) & 3));
            gll16(&Bh[src], &sBh[c * 512]);
            gll16(&Bl[src], &sBl[c * 512]);
        }
        __syncthreads();

        bf16x8 aH[MT], aL[MT], bH[4], bL[4];
        #pragma unroll
        for (int nt = 0; nt < 4; ++nt) {
            const int rn = 64 * wc + 16 * nt + l15;
            const int off = rn * 32 + 8 * (lq ^ ((rn >> 1) & 3));
            bH[nt] = *(const bf16x8*)&sBh[off];
            bL[nt] = *(const bf16x8*)&sBl[off];
        }
        #pragma unroll
        for (int mt = 0; mt < MT; ++mt) {
            const int rm = RW * wr + 16 * mt + l15;
            const int off = rm * 32 + 8 * (lq ^ ((rm >> 1) & 3));
            aH[mt] = *(const bf16x8*)&sAh[off];
            aL[mt] = *(const bf16x8*)&sAl[off];
        }
        #pragma unroll
        for (int mt = 0; mt < MT; ++mt)
            #pragma unroll
            for (int nt = 0; nt < 4; ++nt) {
                acc[mt][nt] = MFMA16(aH[mt], bH[nt], acc[mt][nt]);
                acc[mt][nt] = MFMA16(aH[mt], bL[nt], acc[mt][nt]);
                acc[mt][nt] = MFMA16(aL[mt], bH[nt], acc[mt][nt]);
            }
    }

    if (OUTMODE == 3) {
        // transposed store via LDS bounce: sv[128 c][72 t] bf16, then 128B-
        // coalesced us8 stores along t into V[b][n][d][t].
        __syncthreads();                 // all waves done reading sA/sB
        unsigned short* sv = sm;         // 128*72 = 9216 ushorts <= 12288
        #pragma unroll
        for (int mt = 0; mt < MT; ++mt)
            #pragma unroll
            for (int nt = 0; nt < 4; ++nt) {
                const int cl = 64 * wc + 16 * nt + l15;
                const float bb = bias0[col0 + cl];
                #pragma unroll
                for (int r = 0; r < 4; ++r) {
                    const int tl = RW * wr + 16 * mt + 4 * lq + r;
                    sv[cl * 72 + tl] = f2bf(acc[mt][nt][r] + bb);
                }
            }
        __syncthreads();
        const int b = row0 >> 11, t0 = row0 & 2047;
        #pragma unroll
        for (int it = 0; it < 4; ++it) {
            const int cl = it * 32 + (t >> 3);
            const int ts = (t & 7) * 8;
            const us8 o8 = *(const us8*)&sv[cl * 72 + ts];
            const int c = col0 + cl;
            *(us8*)&Oh[((size_t)((b * 16 + (c >> 6)) * 64 + (c & 63))) * 2048 + t0 + ts] = o8;
        }
        return;
    }

    // LDS-bounce epilogue, two 32-col passes (fits LDS exactly for BM=128)
    __syncthreads();   // all waves done reading sA/sB
    float* sc = (float*)sm + w * (RW * 32);
    #pragma unroll
    for (int h = 0; h < 2; ++h) {
        #pragma unroll
        for (int mt = 0; mt < MT; ++mt)
            #pragma unroll
            for (int nt2 = 0; nt2 < 2; ++nt2) {
                const int nt = 2 * h + nt2;
                const int colg = col0 + 64 * wc + 16 * nt + l15;
                float bb;
                if (OUTMODE == 0) bb = (col0 < 1024) ? bias0[colg] : bias1[colg - 1024];
                else bb = bias0[colg];
                const int cl = 16 * nt2 + l15;
                #pragma unroll
                for (int r = 0; r < 4; ++r) {
                    const int row = 16 * mt + 4 * lq + r;
                    sc[row * 32 + 4 * ((cl >> 2) ^ (row & 7)) + (cl & 3)] = acc[mt][nt][r] + bb;
                }
            }
        asm volatile("" ::: "memory");
        #pragma unroll
        for (int it = 0; it < RW / 16; ++it) {
            const int rl = it * 16 + (lane >> 2);
            const int c8 = (lane & 3) * 8;
            const float4 f0 = *(const float4*)&sc[rl * 32 + 4 * ((c8 >> 2) ^ (rl & 7))];
            const float4 f1 = *(const float4*)&sc[rl * 32 + 4 * (((c8 >> 2) + 1) ^ (rl & 7))];
            const int gr = row0 + RW * wr + rl;
            const int gc = col0 + 64 * wc + 32 * h + c8;
            if (OUTMODE == 2) {
                *(float4*)&Of[(size_t)gr * 1024 + gc] = f0;
                *(float4*)&Of[(size_t)gr * 1024 + gc + 4] = f1;
            } else {
                const float v[8] = {f0.x, f0.y, f0.z, f0.w, f1.x, f1.y, f1.z, f1.w};
                us8 H, L;
                #pragma unroll
                for (int j = 0; j < 8; ++j) {
                    const unsigned short hh = f2bf(v[j]);
                    H[j] = hh;
                    L[j] = f2bf(v[j] - bf2f(hh));
                }
                *(us8*)&Oh[(size_t)gr * 2048 + gc] = H;
                *(us8*)&Ol[(size_t)gr * 2048 + gc] = L;
            }
        }
        asm volatile("" ::: "memory");
    }
}

// ---------------------------------------------------------------------------
// Flash attention v2 (swapped roles). QK buffer [4096][2048]: cols 0-1023 =
// q-proj (column side), 1024-2047 = k-proj (row side). V pre-transposed
// [b][n][64 d][2048 t]. Q frags hoisted; sP aliases dead sQ (40 KB LDS);
// defer-max; setprio around MFMA clusters.
// launch_bounds min-waves = 2 (NOT 4): the 4-wave bound forced VGPR<=64 and
// spilled the flash loop to scratch (r5: WRITE_SIZE +28MB, MfmaUtil down).
__global__ __launch_bounds__(256, 2)
void attn2(const unsigned short* __restrict__ QKh, const unsigned short* __restrict__ QKl,
           const unsigned short* __restrict__ Vt,
           unsigned short* __restrict__ Oh, unsigned short* __restrict__ Ol) {
    __shared__ __align__(16) unsigned short sm[20480];   // 40 KB
    unsigned short* sQh = sm;            // [64][64] (dead after hoist; sP aliases)
    unsigned short* sQl = sm + 4096;
    unsigned short* sKh = sm + 8192;
    unsigned short* sKl = sm + 12288;
    unsigned short* sVt = sm + 16384;    // [64 d][64 t]
    unsigned short* sP  = sm;            // 4 waves x [16][64]

    const int t = threadIdx.x;
    const int lane = t & 63, w = t >> 6;
    const int l15 = lane & 15, lq = lane >> 4;
    const int bn = blockIdx.x;
    const int b = bn >> 4, n = bn & 15;
    const int qt = (gridDim.y - 1) - blockIdx.y;         // heavy tiles first
    const int rowQ0 = b * TT + qt * 64;
    const int colQ = 1024 + n * 64;                      // row side = k-proj
    const int colK = n * 64;                             // col side = q-proj

    // stage Q tile (row side), hi+lo
    #pragma unroll
    for (int cc = 0; cc < 2; ++cc) {
        const int c = w * 2 + cc;
        const int r = 8 * c + (lane >> 3);
        const int src = (rowQ0 + r) * 2048 + colQ + 8 * ((lane & 7) ^ (r & 7));
        gll16(&QKh[src], &sQh[c * 512]);
        gll16(&QKl[src], &sQl[c * 512]);
    }
    __syncthreads();
    // hoist Q fragments (loop-invariant)
    bf16x8 qH[2], qL[2];
    #pragma unroll
    for (int kh = 0; kh < 2; ++kh) {
        const int rq = 16 * w + l15;
        const int off = rq * 64 + 8 * ((lq + 4 * kh) ^ (rq & 7));
        qH[kh] = *(const bf16x8*)&sQh[off];
        qL[kh] = *(const bf16x8*)&sQl[off];
    }

    float m_[4], l_[4];
    f32x4 o[4] = {};
    #pragma unroll
    for (int r = 0; r < 4; ++r) { m_[r] = -1e30f; l_[r] = 0.f; }

    for (int kt = 0; kt <= qt; ++kt) {
        const int rowK0 = b * TT + kt * 64;
        __syncthreads();                                  // prev iter done with LDS
        #pragma unroll
        for (int cc = 0; cc < 2; ++cc) {                  // K hi/lo (col side)
            const int c = w * 2 + cc;
            const int r = 8 * c + (lane >> 3);
            const int src = (rowK0 + r) * 2048 + colK + 8 * ((lane & 7) ^ (r & 7));
            gll16(&QKh[src], &sKh[c * 512]);
            gll16(&QKl[src], &sKl[c * 512]);
        }
        #pragma unroll
        for (int cc = 0; cc < 2; ++cc) {                  // V (pre-transposed rows d)
            const int c = w * 2 + cc;
            const int r = 8 * c + (lane >> 3);
            const int src = (bn * 64 + r) * 2048 + kt * 64 + 8 * ((lane & 7) ^ (r & 7));
            gll16(&Vt[src], &sVt[c * 512]);
        }
        __syncthreads();

        // ---- QK^T (split: 3 MFMA per 16x16x32)
        f32x4 s[4] = {};
        const int njt = (kt == qt) ? (w + 1) : 4;         // skip fully-masked tiles
        __builtin_amdgcn_s_setprio(1);
        #pragma unroll
        for (int kh = 0; kh < 2; ++kh) {
            #pragma unroll
            for (int jt = 0; jt < 4; ++jt) {
                if (jt >= njt) continue;                  // wave-uniform
                const int rk = 16 * jt + l15;
                const int offk = rk * 64 + 8 * ((lq + 4 * kh) ^ (rk & 7));
                const bf16x8 kH = *(const bf16x8*)&sKh[offk];
                const bf16x8 kL = *(const bf16x8*)&sKl[offk];
                s[jt] = MFMA16(qH[kh], kH, s[jt]);
                s[jt] = MFMA16(qH[kh], kL, s[jt]);
                s[jt] = MFMA16(qL[kh], kH, s[jt]);
            }
        }
        __builtin_amdgcn_s_setprio(0);
        if (kt == qt) {                                    // causal mask on diagonal
            #pragma unroll
            for (int jt = 0; jt < 4; ++jt)
                #pragma unroll
                for (int r = 0; r < 4; ++r)
                    if (16 * jt + l15 > 16 * w + 4 * lq + r) s[jt][r] = -1e30f;
        }

        // ---- online softmax with defer-max (THR=16 raw logits -> exp arg <= 2)
        float mx[4];
        int need = 0;
        #pragma unroll
        for (int r = 0; r < 4; ++r) {
            float m0 = fmaxf(fmaxf(s[0][r], s[1][r]), fmaxf(s[2][r], s[3][r]));
            #pragma unroll
            for (int off = 8; off; off >>= 1) m0 = fmaxf(m0, __shfl_xor(m0, off, 16));
            mx[r] = m0;
            need |= (m0 > m_[r] + 16.f) ? 1 : 0;
        }
        float po[4][4];
        if (__any(need)) {
            #pragma unroll
            for (int r = 0; r < 4; ++r) {
                const float mnew = fmaxf(m_[r], mx[r]);
                const float alpha = __expf((m_[r] - mnew) * 0.125f);
                m_[r] = mnew;
                float ps = 0.f;
                #pragma unroll
                for (int jt = 0; jt < 4; ++jt) {
                    const float p = __expf((s[jt][r] - mnew) * 0.125f);
                    po[r][jt] = p;
                    ps += p;
                }
                #pragma unroll
                for (int off = 8; off; off >>= 1) ps += __shfl_xor(ps, off, 16);
                l_[r] = l_[r] * alpha + ps;
                #pragma unroll
                for (int dt = 0; dt < 4; ++dt) o[dt][r] *= alpha;
            }
        } else {
            #pragma unroll
            for (int r = 0; r < 4; ++r) {
                float ps = 0.f;
                #pragma unroll
                for (int jt = 0; jt < 4; ++jt) {
                    const float p = __expf((s[jt][r] - m_[r]) * 0.125f);
                    po[r][jt] = p;
                    ps += p;
                }
                #pragma unroll
                for (int off = 8; off; off >>= 1) ps += __shfl_xor(ps, off, 16);
                l_[r] += ps;
            }
        }
        // write P (bf16) to per-wave LDS region (aliases dead sQ)
        unsigned short* Pw = sP + w * 1024;
        #pragma unroll
        for (int r = 0; r < 4; ++r) {
            const int rl = 4 * lq + r;
            #pragma unroll
            for (int jt = 0; jt < 4; ++jt) {
                const int c = 16 * jt + l15;
                Pw[rl * 64 + 8 * ((c >> 3) ^ (rl & 7)) + (c & 7)] = f2bf(po[r][jt]);
            }
        }
        __syncthreads();

        // ---- PV (plain bf16; V already transposed in LDS)
        __builtin_amdgcn_s_setprio(1);
        #pragma unroll
        for (int kh = 0; kh < 2; ++kh) {
            const int offp = l15 * 64 + 8 * ((lq + 4 * kh) ^ (l15 & 7));
            const bf16x8 pa = *(const bf16x8*)&Pw[offp];
            #pragma unroll
            for (int dt = 0; dt < 4; ++dt) {
                const int rd = 16 * dt + l15;
                const int offv = rd * 64 + 8 * ((lq + 4 * kh) ^ (rd & 7));
                const bf16x8 vb = *(const bf16x8*)&sVt[offv];
                o[dt] = MFMA16(pa, vb, o[dt]);
            }
        }
        __builtin_amdgcn_s_setprio(0);
    }

    // ---- epilogue: normalize, bounce through LDS, store hi/lo bf16
    __syncthreads();   // sP aliases sc region across waves — drain loop reads
    float inv[4];
    #pragma unroll
    for (int r = 0; r < 4; ++r) inv[r] = 1.0f / l_[r];
    float* sc = (float*)sm + w * (16 * 68);
    #pragma unroll
    for (int dt = 0; dt < 4; ++dt)
        #pragma unroll
        for (int r = 0; r < 4; ++r)
            sc[(4 * lq + r) * 68 + 16 * dt + l15] = o[dt][r] * inv[r];
    asm volatile("" ::: "memory");
    #pragma unroll
    for (int it = 0; it < 2; ++it) {
        const int rl = 8 * it + (lane >> 3);
        const int c8 = (lane & 7) * 8;
        const float4 f0 = *(const float4*)&sc[rl * 68 + c8];
        const float4 f1 = *(const float4*)&sc[rl * 68 + c8 + 4];
        const float v[8] = {f0.x, f0.y, f0.z, f0.w, f1.x, f1.y, f1.z, f1.w};
        us8 H, L;
        #pragma unroll
        for (int j = 0; j < 8; ++j) {
            const unsigned short h = f2bf(v[j]);
            H[j] = h;
            L[j] = f2bf(v[j] - bf2f(h));
        }
        const int gt = rowQ0 + 16 * w + rl;
        *(us8*)&Oh[(size_t)gt * 1024 + (n * 64) + c8] = H;
        *(us8*)&Ol[(size_t)gt * 1024 + (n * 64) + c8] = L;
    }
}

// ---------------------------------------------------------------------------
extern "C" void kernel_launch(void* const* d_in, const int* in_sizes, int n_in,
                              void* d_out, int out_size, void* d_ws, size_t ws_size,
                              hipStream_t stream) {
    const float* x  = (const float*)d_in[0];
    const float* Wq = (const float*)d_in[1];
    const float* bq = (const float*)d_in[2];
    const float* Wk = (const float*)d_in[3];
    const float* bk = (const float*)d_in[4];
    const float* Wv = (const float*)d_in[5];
    const float* bv = (const float*)d_in[6];
    const float* Wp = (const float*)d_in[7];
    const float* bp = (const float*)d_in[8];
    float* out = (float*)d_out;

    char* p = (char*)d_ws;                                 // peak 64 MiB exactly
    const size_t MB = 1024 * 1024;
    unsigned short* xh  = (unsigned short*)(p);            //  8 MB
    unsigned short* xl  = (unsigned short*)(p +  8 * MB);  //  8 MB
    unsigned short* qkh = (unsigned short*)(p + 16 * MB);  // 16 MB [4096][2048]
    unsigned short* qkl = (unsigned short*)(p + 32 * MB);  // 16 MB
    unsigned short* vh  = (unsigned short*)(p + 48 * MB);  //  8 MB [32][64][2048]
    unsigned short* wbh = (unsigned short*)(p + 56 * MB);  //  4 MB (QK Bt hi)
    unsigned short* wbl = (unsigned short*)(p + 60 * MB);  //  4 MB (QK Bt lo)
    unsigned short* wsh = (unsigned short*)(p + 56 * MB);  //  2 MB (single-W hi)
    unsigned short* wsl = (unsigned short*)(p + 58 * MB);  //  2 MB (single-W lo)
    unsigned short* oh = xh;                               // x dead after projections
    unsigned short* ol = xl;

    const dim3 blk(256);
    const dim3 gw(32, 32);

    convert_x<<<2048, blk, 0, stream>>>(x, xh, xl);

    // fused q+k projection: Bt rows 0-1023 = Wq, 1024-2047 = Wk
    convert_w<<<gw, blk, 0, stream>>>(Wq, wbh, wbl);
    convert_w<<<gw, blk, 0, stream>>>(Wk, wbh + 1024 * 1024, wbl + 1024 * 1024);
    proj2<128, 0><<<dim3(32, 16), blk, 0, stream>>>(xh, xl, wbh, wbl, bq, bk,
                                                    qkh, qkl, nullptr);
    // v projection, output pre-transposed [b][n][d][t]
    convert_w<<<gw, blk, 0, stream>>>(Wv, wsh, wsl);
    proj2<64, 3><<<dim3(64, 8), blk, 0, stream>>>(xh, xl, wsh, wsl, bv, nullptr,
                                                  vh, nullptr, nullptr);

    attn2<<<dim3(32, 32), blk, 0, stream>>>(qkh, qkl, vh, oh, ol);

    // final projection -> fp32 out
    convert_w<<<gw, blk, 0, stream>>>(Wp, wsh, wsl);
    proj2<64, 2><<<dim3(64, 8), blk, 0, stream>>>(oh, ol, wsh, wsl, bp, nullptr,
                                                  nullptr, nullptr, out);
}

// Round 10
// 312.276 us; speedup vs baseline: 1.0367x; 1.0138x over previous
//
#include <hip/hip_runtime.h>
#include <hip/hip_bf16.h>

#define TT 2048

typedef __attribute__((ext_vector_type(8))) short bf16x8;
typedef __attribute__((ext_vector_type(4))) float f32x4;
typedef __attribute__((ext_vector_type(8))) unsigned short us8;
typedef __attribute__((ext_vector_type(4))) unsigned short us4;

typedef __attribute__((address_space(1))) void gvoid;
typedef __attribute__((address_space(3))) void svoid;

__device__ __forceinline__ void gll16(const void* g, void* l) {
    __builtin_amdgcn_global_load_lds((gvoid*)g, (svoid*)l, 16, 0, 0);
}

__device__ __forceinline__ unsigned short f2bf(float f) {
    union { float f; unsigned u; } v; v.f = f;
    unsigned r = v.u + 0x7fffu + ((v.u >> 16) & 1u);
    return (unsigned short)(r >> 16);
}
__device__ __forceinline__ float bf2f(unsigned short u) {
    union { unsigned u; float f; } v; v.u = ((unsigned)u) << 16;
    return v.f;
}

#define MFMA16(a, b, c) __builtin_amdgcn_mfma_f32_16x16x32_bf16((a), (b), (c), 0, 0, 0)

// ---------------------------------------------------------------------------
// x fp32 -> hi/lo bf16 (row-major). 4096*1024 elements, 8/thread.
__global__ __launch_bounds__(256) void convert_x(const float* __restrict__ x,
                                                 unsigned short* __restrict__ xh,
                                                 unsigned short* __restrict__ xl) {
    const int i = blockIdx.x * 256 + threadIdx.x;
    const float4 a = ((const float4*)x)[2 * i];
    const float4 b = ((const float4*)x)[2 * i + 1];
    const float v[8] = {a.x, a.y, a.z, a.w, b.x, b.y, b.z, b.w};
    us8 H, L;
    #pragma unroll
    for (int j = 0; j < 8; ++j) {
        const unsigned short h = f2bf(v[j]);
        H[j] = h;
        L[j] = f2bf(v[j] - bf2f(h));
    }
    ((us8*)xh)[i] = H;
    ((us8*)xl)[i] = L;
}

// ---------------------------------------------------------------------------
// One weight [1024][1024] fp32 -> hi/lo bf16 [n][k] (transposed).
__global__ __launch_bounds__(256) void convert_w(const float* __restrict__ W,
                                                 unsigned short* __restrict__ Wh,
                                                 unsigned short* __restrict__ Wl) {
    __shared__ float tile[32 * 33];
    const int t = threadIdx.x;
    const int k0 = blockIdx.x * 32, n0 = blockIdx.y * 32;

    const int kl_ = t >> 3, nc = (t & 7) * 4;
    const float4 v = *(const float4*)&W[(size_t)(k0 + kl_) * 1024 + n0 + nc];
    tile[(nc + 0) * 33 + kl_] = v.x;
    tile[(nc + 1) * 33 + kl_] = v.y;
    tile[(nc + 2) * 33 + kl_] = v.z;
    tile[(nc + 3) * 33 + kl_] = v.w;
    __syncthreads();
    const int nl = t >> 3, kc = (t & 7) * 4;
    us4 H, L;
    #pragma unroll
    for (int j = 0; j < 4; ++j) {
        const float f = tile[nl * 33 + kc + j];
        const unsigned short h = f2bf(f);
        H[j] = h;
        L[j] = f2bf(f - bf2f(h));
    }
    *(us4*)&Wh[(size_t)(n0 + nl) * 1024 + k0 + kc] = H;
    *(us4*)&Wl[(size_t)(n0 + nl) * 1024 + k0 + kc] = L;
}

// ---------------------------------------------------------------------------
// Split-bf16 GEMM v3: double-buffered 2-phase pipeline (T3-lite, m248v2):
// stage(k+1 into buf^1) is issued BEFORE compute(buf cur); ONE barrier per
// K-step drains loads that overlapped ~500cy of MFMA (was: 2 barriers + fully
// exposed load latency each step -> ~53us/unit at 2 blocks/CU).
// OUTMODE 0: hi/lo bf16 out, stride 2048 (fused QK; bias0=cols<1024, bias1=rest)
// OUTMODE 2: fp32 out, stride 1024
// OUTMODE 3: bf16 hi out TRANSPOSED as V[b][n][d][t], coalesced via LDS bounce
template <int BM, int OUTMODE>
__global__ __launch_bounds__(256, 2)
void proj2(const unsigned short* __restrict__ Ah, const unsigned short* __restrict__ Al,
           const unsigned short* __restrict__ Bh, const unsigned short* __restrict__ Bl,
           const float* __restrict__ bias0, const float* __restrict__ bias1,
           unsigned short* __restrict__ Oh, unsigned short* __restrict__ Ol,
           float* __restrict__ Of) {
    constexpr int MT = BM / 32;          // m-frags per wave (4 or 2)
    constexpr int RW = BM / 2;           // rows per wave
    constexpr int CA = BM / 64;          // A chunks per wave per buffer
    constexpr int BUFU = BM * 64 + 8192; // ushorts per buffer (A hi/lo + B hi/lo)
    __shared__ __align__(16) unsigned short sm[2 * BUFU];   // 64 KB (BM=128)

    const int t = threadIdx.x;
    const int lane = t & 63, w = t >> 6;
    const int wr = w >> 1, wc = w & 1;
    const int l15 = lane & 15, lq = lane >> 4;

    // XCD-aware bijective swizzle (nwg % 8 == 0 for all our grids)
    const int nwg = gridDim.x * gridDim.y;
    const int bid = blockIdx.y * gridDim.x + blockIdx.x;
    const int swz = (bid & 7) * (nwg >> 3) + (bid >> 3);
    const int bx = swz % gridDim.x, by = swz / gridDim.x;
    const int row0 = bx * BM;
    const int col0 = by * 128;

    // stage K-tile k0 into buffer `base` (pre-swizzled global src, linear dest)
    auto stage = [&](int k0, unsigned short* base) {
        #pragma unroll
        for (int cc = 0; cc < CA; ++cc) {        // A tile: hi + lo
            const int c = w * CA + cc;
            const int r = c * 16 + (lane >> 2);
            const int src = (row0 + r) * 1024 + k0 + 8 * ((lane & 3) ^ ((r >> 1) & 3));
            gll16(&Ah[src], &base[c * 512]);
            gll16(&Al[src], &base[BM * 32 + c * 512]);
        }
        #pragma unroll
        for (int cc = 0; cc < 2; ++cc) {         // B tile (128 rows)
            const int c = w * 2 + cc;
            const int r = c * 16 + (lane >> 2);
            const int src = (col0 + r) * 1024 + k0 + 8 * ((lane & 3) ^ ((r >> 1) & 3));
            gll16(&Bh[src], &base[BM * 64 + c * 512]);
            gll16(&Bl[src], &base[BM * 64 + 4096 + c * 512]);
        }
    };

    f32x4 acc[MT][4] = {};

    stage(0, sm);                 // prologue: fill buffer 0
    __syncthreads();
    int cur = 0;

    for (int k0 = 0; k0 < 1024; k0 += 32) {
        unsigned short* base = sm + cur * BUFU;
        if (k0 + 32 < 1024) stage(k0 + 32, sm + (cur ^ 1) * BUFU);  // overlap

        bf16x8 aH[MT], aL[MT], bH[4], bL[4];
        #pragma unroll
        for (int nt = 0; nt < 4; ++nt) {
            const int rn = 64 * wc + 16 * nt + l15;
            const int off = rn * 32 + 8 * (lq ^ ((rn >> 1) & 3));
            bH[nt] = *(const bf16x8*)&base[BM * 64 + off];
            bL[nt] = *(const bf16x8*)&base[BM * 64 + 4096 + off];
        }
        #pragma unroll
        for (int mt = 0; mt < MT; ++mt) {
            const int rm = RW * wr + 16 * mt + l15;
            const int off = rm * 32 + 8 * (lq ^ ((rm >> 1) & 3));
            aH[mt] = *(const bf16x8*)&base[off];
            aL[mt] = *(const bf16x8*)&base[BM * 32 + off];
        }
        __builtin_amdgcn_s_setprio(1);
        #pragma unroll
        for (int mt = 0; mt < MT; ++mt)
            #pragma unroll
            for (int nt = 0; nt < 4; ++nt) {
                acc[mt][nt] = MFMA16(aH[mt], bH[nt], acc[mt][nt]);
                acc[mt][nt] = MFMA16(aH[mt], bL[nt], acc[mt][nt]);
                acc[mt][nt] = MFMA16(aL[mt], bH[nt], acc[mt][nt]);
            }
        __builtin_amdgcn_s_setprio(0);
        __syncthreads();          // drains overlapped stage + guards buffer swap
        cur ^= 1;
    }

    if (OUTMODE == 3) {
        // transposed store via LDS bounce: sv[128 c][72 t] bf16, then 128B-
        // coalesced us8 stores along t into V[b][n][d][t].
        unsigned short* sv = sm;         // buffers dead after final barrier
        #pragma unroll
        for (int mt = 0; mt < MT; ++mt)
            #pragma unroll
            for (int nt = 0; nt < 4; ++nt) {
                const int cl = 64 * wc + 16 * nt + l15;
                const float bb = bias0[col0 + cl];
                #pragma unroll
                for (int r = 0; r < 4; ++r) {
                    const int tl = RW * wr + 16 * mt + 4 * lq + r;
                    sv[cl * 72 + tl] = f2bf(acc[mt][nt][r] + bb);
                }
            }
        __syncthreads();
        const int b = row0 >> 11, t0 = row0 & 2047;
        #pragma unroll
        for (int it = 0; it < 4; ++it) {
            const int cl = it * 32 + (t >> 3);
            const int ts = (t & 7) * 8;
            const us8 o8 = *(const us8*)&sv[cl * 72 + ts];
            const int c = col0 + cl;
            *(us8*)&Oh[((size_t)((b * 16 + (c >> 6)) * 64 + (c & 63))) * 2048 + t0 + ts] = o8;
        }
        return;
    }

    // LDS-bounce epilogue, two 32-col passes (buffers dead after final barrier)
    float* sc = (float*)sm + w * (RW * 32);
    #pragma unroll
    for (int h = 0; h < 2; ++h) {
        #pragma unroll
        for (int mt = 0; mt < MT; ++mt)
            #pragma unroll
            for (int nt2 = 0; nt2 < 2; ++nt2) {
                const int nt = 2 * h + nt2;
                const int colg = col0 + 64 * wc + 16 * nt + l15;
                float bb;
                if (OUTMODE == 0) bb = (col0 < 1024) ? bias0[colg] : bias1[colg - 1024];
                else bb = bias0[colg];
                const int cl = 16 * nt2 + l15;
                #pragma unroll
                for (int r = 0; r < 4; ++r) {
                    const int row = 16 * mt + 4 * lq + r;
                    sc[row * 32 + 4 * ((cl >> 2) ^ (row & 7)) + (cl & 3)] = acc[mt][nt][r] + bb;
                }
            }
        asm volatile("" ::: "memory");
        #pragma unroll
        for (int it = 0; it < RW / 16; ++it) {
            const int rl = it * 16 + (lane >> 2);
            const int c8 = (lane & 3) * 8;
            const float4 f0 = *(const float4*)&sc[rl * 32 + 4 * ((c8 >> 2) ^ (rl & 7))];
            const float4 f1 = *(const float4*)&sc[rl * 32 + 4 * (((c8 >> 2) + 1) ^ (rl & 7))];
            const int gr = row0 + RW * wr + rl;
            const int gc = col0 + 64 * wc + 32 * h + c8;
            if (OUTMODE == 2) {
                *(float4*)&Of[(size_t)gr * 1024 + gc] = f0;
                *(float4*)&Of[(size_t)gr * 1024 + gc + 4] = f1;
            } else {
                const float v[8] = {f0.x, f0.y, f0.z, f0.w, f1.x, f1.y, f1.z, f1.w};
                us8 H, L;
                #pragma unroll
                for (int j = 0; j < 8; ++j) {
                    const unsigned short hh = f2bf(v[j]);
                    H[j] = hh;
                    L[j] = f2bf(v[j] - bf2f(hh));
                }
                *(us8*)&Oh[(size_t)gr * 2048 + gc] = H;
                *(us8*)&Ol[(size_t)gr * 2048 + gc] = L;
            }
        }
        asm volatile("" ::: "memory");
    }
}

// ---------------------------------------------------------------------------
// Flash attention v3: double-buffered K/V (2-phase) + ONE barrier per kt.
// Was: 3 barriers/kt with stage->barrier->compute exposing full global->LDS
// latency every tile (r9: 87us, MfmaUtil 16%, VALUBusy 37% = latency-bound).
// Now: stage(kt+1 into buf^1) issued before QK/softmax/PV on buf[cur]; the
// post-P barrier removed (P region is strictly per-wave). sP aliases dead sQh
// (wave w's P region == the sQ rows only wave w hoists, no cross-wave race).
__global__ __launch_bounds__(256, 2)
void attn2(const unsigned short* __restrict__ QKh, const unsigned short* __restrict__ QKl,
           const unsigned short* __restrict__ Vt,
           unsigned short* __restrict__ Oh, unsigned short* __restrict__ Ol) {
    constexpr int BUFU = 12288;          // sKh 4096 + sKl 4096 + sVt 4096 us
    __shared__ __align__(16) unsigned short sm[8192 + 2 * BUFU];   // 64 KB
    unsigned short* sQh = sm;            // [64][64] hi (dead after hoist)
    unsigned short* sQl = sm + 4096;
    unsigned short* sP  = sm;            // 4 waves x [16][64], aliases sQh

    const int t = threadIdx.x;
    const int lane = t & 63, w = t >> 6;
    const int l15 = lane & 15, lq = lane >> 4;
    const int bn = blockIdx.x;
    const int b = bn >> 4, n = bn & 15;
    const int qt = (gridDim.y - 1) - blockIdx.y;         // heavy tiles first
    const int rowQ0 = b * TT + qt * 64;
    const int colQ = 1024 + n * 64;                      // row side = k-proj
    const int colK = n * 64;                             // col side = q-proj

    auto stageKV = [&](int kt, unsigned short* base) {
        const int rowK0 = b * TT + kt * 64;
        #pragma unroll
        for (int cc = 0; cc < 2; ++cc) {                 // K hi/lo (col side)
            const int c = w * 2 + cc;
            const int r = 8 * c + (lane >> 3);
            const int src = (rowK0 + r) * 2048 + colK + 8 * ((lane & 7) ^ (r & 7));
            gll16(&QKh[src], &base[c * 512]);
            gll16(&QKl[src], &base[4096 + c * 512]);
        }
        #pragma unroll
        for (int cc = 0; cc < 2; ++cc) {                 // V (pre-transposed rows d)
            const int c = w * 2 + cc;
            const int r = 8 * c + (lane >> 3);
            const int src = (bn * 64 + r) * 2048 + kt * 64 + 8 * ((lane & 7) ^ (r & 7));
            gll16(&Vt[src], &base[8192 + c * 512]);
        }
    };

    // prologue: stage Q tile + first K/V tile, single barrier
    #pragma unroll
    for (int cc = 0; cc < 2; ++cc) {
        const int c = w * 2 + cc;
        const int r = 8 * c + (lane >> 3);
        const int src = (rowQ0 + r) * 2048 + colQ + 8 * ((lane & 7) ^ (r & 7));
        gll16(&QKh[src], &sQh[c * 512]);
        gll16(&QKl[src], &sQl[c * 512]);
    }
    stageKV(0, sm + 8192);
    __syncthreads();

    // hoist Q fragments (loop-invariant; reads only this wave's own sQ rows)
    bf16x8 qH[2], qL[2];
    #pragma unroll
    for (int kh = 0; kh < 2; ++kh) {
        const int rq = 16 * w + l15;
        const int off = rq * 64 + 8 * ((lq + 4 * kh) ^ (rq & 7));
        qH[kh] = *(const bf16x8*)&sQh[off];
        qL[kh] = *(const bf16x8*)&sQl[off];
    }

    float m_[4], l_[4];
    f32x4 o[4] = {};
    #pragma unroll
    for (int r = 0; r < 4; ++r) { m_[r] = -1e30f; l_[r] = 0.f; }

    int cur = 0;
    for (int kt = 0; kt <= qt; ++kt) {
        unsigned short* base = sm + 8192 + cur * BUFU;   // sKh | sKl | sVt
        if (kt < qt) stageKV(kt + 1, sm + 8192 + (cur ^ 1) * BUFU);  // overlap

        // ---- QK^T (split: 3 MFMA per 16x16x32)
        f32x4 s[4] = {};
        const int njt = (kt == qt) ? (w + 1) : 4;         // skip fully-masked tiles
        __builtin_amdgcn_s_setprio(1);
        #pragma unroll
        for (int kh = 0; kh < 2; ++kh) {
            #pragma unroll
            for (int jt = 0; jt < 4; ++jt) {
                if (jt >= njt) continue;                  // wave-uniform
                const int rk = 16 * jt + l15;
                const int offk = rk * 64 + 8 * ((lq + 4 * kh) ^ (rk & 7));
                const bf16x8 kH = *(const bf16x8*)&base[offk];
                const bf16x8 kL = *(const bf16x8*)&base[4096 + offk];
                s[jt] = MFMA16(qH[kh], kH, s[jt]);
                s[jt] = MFMA16(qH[kh], kL, s[jt]);
                s[jt] = MFMA16(qL[kh], kH, s[jt]);
            }
        }
        __builtin_amdgcn_s_setprio(0);
        if (kt == qt) {                                    // causal mask on diagonal
            #pragma unroll
            for (int jt = 0; jt < 4; ++jt)
                #pragma unroll
                for (int r = 0; r < 4; ++r)
                    if (16 * jt + l15 > 16 * w + 4 * lq + r) s[jt][r] = -1e30f;
        }

        // ---- online softmax with defer-max (THR=16 raw logits -> exp arg <= 2)
        float mx[4];
        int need = 0;
        #pragma unroll
        for (int r = 0; r < 4; ++r) {
            float m0 = fmaxf(fmaxf(s[0][r], s[1][r]), fmaxf(s[2][r], s[3][r]));
            #pragma unroll
            for (int off = 8; off; off >>= 1) m0 = fmaxf(m0, __shfl_xor(m0, off, 16));
            mx[r] = m0;
            need |= (m0 > m_[r] + 16.f) ? 1 : 0;
        }
        float po[4][4];
        if (__any(need)) {
            #pragma unroll
            for (int r = 0; r < 4; ++r) {
                const float mnew = fmaxf(m_[r], mx[r]);
                const float alpha = __expf((m_[r] - mnew) * 0.125f);
                m_[r] = mnew;
                float ps = 0.f;
                #pragma unroll
                for (int jt = 0; jt < 4; ++jt) {
                    const float p = __expf((s[jt][r] - mnew) * 0.125f);
                    po[r][jt] = p;
                    ps += p;
                }
                #pragma unroll
                for (int off = 8; off; off >>= 1) ps += __shfl_xor(ps, off, 16);
                l_[r] = l_[r] * alpha + ps;
                #pragma unroll
                for (int dt = 0; dt < 4; ++dt) o[dt][r] *= alpha;
            }
        } else {
            #pragma unroll
            for (int r = 0; r < 4; ++r) {
                float ps = 0.f;
                #pragma unroll
                for (int jt = 0; jt < 4; ++jt) {
                    const float p = __expf((s[jt][r] - m_[r]) * 0.125f);
                    po[r][jt] = p;
                    ps += p;
                }
                #pragma unroll
                for (int off = 8; off; off >>= 1) ps += __shfl_xor(ps, off, 16);
                l_[r] += ps;
            }
        }
        // write P (bf16) to this wave's OWN LDS region — no barrier needed
        unsigned short* Pw = sP + w * 1024;
        #pragma unroll
        for (int r = 0; r < 4; ++r) {
            const int rl = 4 * lq + r;
            #pragma unroll
            for (int jt = 0; jt < 4; ++jt) {
                const int c = 16 * jt + l15;
                Pw[rl * 64 + 8 * ((c >> 3) ^ (rl & 7)) + (c & 7)] = f2bf(po[r][jt]);
            }
        }

        // ---- PV (plain bf16; V transposed in buf[cur], P per-wave)
        __builtin_amdgcn_s_setprio(1);
        #pragma unroll
        for (int kh = 0; kh < 2; ++kh) {
            const int offp = l15 * 64 + 8 * ((lq + 4 * kh) ^ (l15 & 7));
            const bf16x8 pa = *(const bf16x8*)&Pw[offp];
            #pragma unroll
            for (int dt = 0; dt < 4; ++dt) {
                const int rd = 16 * dt + l15;
                const int offv = rd * 64 + 8 * ((lq + 4 * kh) ^ (rd & 7));
                const bf16x8 vb = *(const bf16x8*)&base[8192 + offv];
                o[dt] = MFMA16(pa, vb, o[dt]);
            }
        }
        __builtin_amdgcn_s_setprio(0);

        __syncthreads();    // single barrier: drains overlapped stage, guards swap
        cur ^= 1;
    }

    // ---- epilogue: normalize, bounce through LDS, store hi/lo bf16
    float inv[4];
    #pragma unroll
    for (int r = 0; r < 4; ++r) inv[r] = 1.0f / l_[r];
    float* sc = (float*)sm + w * (16 * 68);   // per-wave region, buffers dead
    #pragma unroll
    for (int dt = 0; dt < 4; ++dt)
        #pragma unroll
        for (int r = 0; r < 4; ++r)
            sc[(4 * lq + r) * 68 + 16 * dt + l15] = o[dt][r] * inv[r];
    asm volatile("" ::: "memory");
    #pragma unroll
    for (int it = 0; it < 2; ++it) {
        const int rl = 8 * it + (lane >> 3);
        const int c8 = (lane & 7) * 8;
        const float4 f0 = *(const float4*)&sc[rl * 68 + c8];
        const float4 f1 = *(const float4*)&sc[rl * 68 + c8 + 4];
        const float v[8] = {f0.x, f0.y, f0.z, f0.w, f1.x, f1.y, f1.z, f1.w};
        us8 H, L;
        #pragma unroll
        for (int j = 0; j < 8; ++j) {
            const unsigned short h = f2bf(v[j]);
            H[j] = h;
            L[j] = f2bf(v[j] - bf2f(h));
        }
        const int gt = rowQ0 + 16 * w + rl;
        *(us8*)&Oh[(size_t)gt * 1024 + (n * 64) + c8] = H;
        *(us8*)&Ol[(size_t)gt * 1024 + (n * 64) + c8] = L;
    }
}

// ---------------------------------------------------------------------------
extern "C" void kernel_launch(void* const* d_in, const int* in_sizes, int n_in,
                              void* d_out, int out_size, void* d_ws, size_t ws_size,
                              hipStream_t stream) {
    const float* x  = (const float*)d_in[0];
    const float* Wq = (const float*)d_in[1];
    const float* bq = (const float*)d_in[2];
    const float* Wk = (const float*)d_in[3];
    const float* bk = (const float*)d_in[4];
    const float* Wv = (const float*)d_in[5];
    const float* bv = (const float*)d_in[6];
    const float* Wp = (const float*)d_in[7];
    const float* bp = (const float*)d_in[8];
    float* out = (float*)d_out;

    char* p = (char*)d_ws;                                 // peak 64 MiB exactly
    const size_t MB = 1024 * 1024;
    unsigned short* xh  = (unsigned short*)(p);            //  8 MB
    unsigned short* xl  = (unsigned short*)(p +  8 * MB);  //  8 MB
    unsigned short* qkh = (unsigned short*)(p + 16 * MB);  // 16 MB [4096][2048]
    unsigned short* qkl = (unsigned short*)(p + 32 * MB);  // 16 MB
    unsigned short* vh  = (unsigned short*)(p + 48 * MB);  //  8 MB [32][64][2048]
    unsigned short* wbh = (unsigned short*)(p + 56 * MB);  //  4 MB (QK Bt hi)
    unsigned short* wbl = (unsigned short*)(p + 60 * MB);  //  4 MB (QK Bt lo)
    unsigned short* wsh = (unsigned short*)(p + 56 * MB);  //  2 MB (single-W hi)
    unsigned short* wsl = (unsigned short*)(p + 58 * MB);  //  2 MB (single-W lo)
    unsigned short* oh = xh;                               // x dead after projections
    unsigned short* ol = xl;

    const dim3 blk(256);
    const dim3 gw(32, 32);

    convert_x<<<2048, blk, 0, stream>>>(x, xh, xl);

    // fused q+k projection: Bt rows 0-1023 = Wq, 1024-2047 = Wk
    convert_w<<<gw, blk, 0, stream>>>(Wq, wbh, wbl);
    convert_w<<<gw, blk, 0, stream>>>(Wk, wbh + 1024 * 1024, wbl + 1024 * 1024);
    proj2<128, 0><<<dim3(32, 16), blk, 0, stream>>>(xh, xl, wbh, wbl, bq, bk,
                                                    qkh, qkl, nullptr);
    // v projection, output pre-transposed [b][n][d][t]
    convert_w<<<gw, blk, 0, stream>>>(Wv, wsh, wsl);
    proj2<64, 3><<<dim3(64, 8), blk, 0, stream>>>(xh, xl, wsh, wsl, bv, nullptr,
                                                  vh, nullptr, nullptr);

    attn2<<<dim3(32, 32), blk, 0, stream>>>(qkh, qkl, vh, oh, ol);

    // final projection -> fp32 out
    convert_w<<<gw, blk, 0, stream>>>(Wp, wsh, wsl);
    proj2<64, 2><<<dim3(64, 8), blk, 0, stream>>>(oh, ol, wsh, wsl, bp, nullptr,
                                                  nullptr, nullptr, out);
}